// Round 1
// baseline (417.192 us; speedup 1.0000x reference)
//
#include <hip/hip_runtime.h>
#include <hip/hip_bf16.h>
#include <stdint.h>

// Problem dims (fixed by setup_inputs): B=4, S=2048 -> M=8192; IN=K=4096; OUT=N=4096; R=16
#define M_DIM 8192
#define N_DIM 4096
#define K_DIM 4096
#define R_DIM 16

typedef __bf16 bf16x8 __attribute__((ext_vector_type(8)));
typedef float f32x4 __attribute__((ext_vector_type(4)));
typedef unsigned short u16x8 __attribute__((ext_vector_type(8)));

#define AS1(p) ((const __attribute__((address_space(1))) void*)(p))
#define AS3(p) ((__attribute__((address_space(3))) void*)(p))

__device__ __forceinline__ unsigned short f2bf(float f) {
  unsigned u = __builtin_bit_cast(unsigned, f);
  u += 0x7FFFu + ((u >> 16) & 1u);   // round-to-nearest-even
  return (unsigned short)(u >> 16);
}

// ---------------------------------------------------------------------------
// Adapted weight: awb[o,i] = bf16( W[o,i] * (1 + sum_r A[r,i]*B[o,r]) )
// grid: (K/512, N/32), block 256. A-panel + B-panel staged in LDS.
// ---------------------------------------------------------------------------
__global__ void __launch_bounds__(256) aw_kernel(
    const float* __restrict__ W, const float* __restrict__ lA,
    const float* __restrict__ lB, unsigned short* __restrict__ awb) {
  __shared__ float Asub[16 * 512];   // 32 KB: lora_A[r][i0..i0+511]
  __shared__ float Bsub[32 * 16];    //  2 KB: lora_B[o0..o0+31][r]
  const int i0 = blockIdx.x * 512;
  const int o0 = blockIdx.y * 32;
  const int tid = threadIdx.x;

  for (int idx = tid; idx < 16 * 512; idx += 256) {
    int r = idx >> 9, i = idx & 511;
    Asub[idx] = lA[r * K_DIM + i0 + i];
  }
  for (int idx = tid; idx < 32 * 16; idx += 256) {
    int o = idx >> 4, r = idx & 15;
    Bsub[idx] = lB[(o0 + o) * R_DIM + r];
  }
  __syncthreads();

  for (int idx = tid; idx < 32 * 512; idx += 256) {
    int o = idx >> 9, i = idx & 511;   // consecutive tid -> consecutive i (coalesced)
    float s = 1.0f;
#pragma unroll
    for (int r = 0; r < 16; ++r) s += Asub[r * 512 + i] * Bsub[o * 16 + r];
    size_t g = (size_t)(o0 + o) * K_DIM + i0 + i;
    awb[g] = f2bf(W[g] * s);
  }
}

// ---------------------------------------------------------------------------
// x (fp32) -> bf16 bits, 8 elems/thread/iter, vectorized.
// ---------------------------------------------------------------------------
__global__ void __launch_bounds__(256) cvt_kernel(const float* __restrict__ x,
                                                  unsigned short* __restrict__ xb) {
  const long total = (long)M_DIM * K_DIM;
  long i = ((long)blockIdx.x * 256 + threadIdx.x) * 8;
  const long stride = (long)gridDim.x * 256 * 8;
  for (; i < total; i += stride) {
    const float4* p = (const float4*)(x + i);
    float4 f0 = p[0], f1 = p[1];
    u16x8 v;
    v[0] = f2bf(f0.x); v[1] = f2bf(f0.y); v[2] = f2bf(f0.z); v[3] = f2bf(f0.w);
    v[4] = f2bf(f1.x); v[5] = f2bf(f1.y); v[6] = f2bf(f1.z); v[7] = f2bf(f1.w);
    *(u16x8*)(xb + i) = v;
  }
}

// ---------------------------------------------------------------------------
// GEMM: out[m,n] = sum_k xb[m,k]*awb[n,k] + bias[n]   (m97 structure)
// 128x128 tile, BK=32, 256 thr = 4 waves (2x2), each wave 64x64 = 4x4 frags
// of mfma_f32_16x16x32_bf16. global_load_lds width=16, 2 barriers/K-step.
// ---------------------------------------------------------------------------
#define BM 128
#define BN 128
#define BK 32

__global__ void __launch_bounds__(256, 2) gemm_kernel(
    const unsigned short* __restrict__ Ag,   // [M][K] bf16 bits
    const unsigned short* __restrict__ Bg,   // [N][K] bf16 bits
    const float* __restrict__ bias,
    float* __restrict__ out) {
  __shared__ unsigned short As[BM * BK];  // 8 KB
  __shared__ unsigned short Bs[BN * BK];  // 8 KB

  // Bijective XCD swizzle: grid = 64*32 = 2048, 2048 % 8 == 0.
  const int nwg = gridDim.x;
  const int q = nwg >> 3;
  const int wg = blockIdx.x;
  const int swz = (wg & 7) * q + (wg >> 3);
  const int tiles_n = N_DIM / BN;          // 32
  const int brow = (swz / tiles_n) * BM;
  const int bcol = (swz % tiles_n) * BN;

  const int tid = threadIdx.x;
  const int lane = tid & 63;
  const int w = tid >> 6;                  // wave 0..3
  const int wr = w >> 1, wc = w & 1;       // 2x2 wave grid

  // Staging map: chunk = c*256 + w*64 + lane; row = chunk>>2; col = (lane&3)*8
  const int srow = w * 16 + (lane >> 2);
  const int scol = (lane & 3) * 8;
  const unsigned short* aSrc = Ag + (size_t)(brow + srow) * K_DIM + scol;
  const unsigned short* bSrc = Bg + (size_t)(bcol + srow) * K_DIM + scol;
  unsigned short* aDst = &As[w * 512];     // + lane*8 elems applied by HW
  unsigned short* bDst = &Bs[w * 512];

  f32x4 acc[4][4] = {};

  const int fr = lane & 15;
  const int kq = (lane >> 4) * 8;

  for (int kt = 0; kt < K_DIM / BK; ++kt) {
    const int k0 = kt * BK;
    __builtin_amdgcn_global_load_lds(AS1(aSrc + k0), AS3(aDst), 16, 0, 0);
    __builtin_amdgcn_global_load_lds(AS1(aSrc + (size_t)64 * K_DIM + k0), AS3(aDst + 2048), 16, 0, 0);
    __builtin_amdgcn_global_load_lds(AS1(bSrc + k0), AS3(bDst), 16, 0, 0);
    __builtin_amdgcn_global_load_lds(AS1(bSrc + (size_t)64 * K_DIM + k0), AS3(bDst + 2048), 16, 0, 0);
    __syncthreads();   // compiler emits s_waitcnt vmcnt(0) before s_barrier

    bf16x8 a[4], b[4];
#pragma unroll
    for (int m = 0; m < 4; ++m)
      a[m] = *(const bf16x8*)&As[(wr * 64 + m * 16 + fr) * BK + kq];
#pragma unroll
    for (int n = 0; n < 4; ++n)
      b[n] = *(const bf16x8*)&Bs[(wc * 64 + n * 16 + fr) * BK + kq];

#pragma unroll
    for (int m = 0; m < 4; ++m)
#pragma unroll
      for (int n = 0; n < 4; ++n)
        acc[m][n] = __builtin_amdgcn_mfma_f32_16x16x32_bf16(a[m], b[n], acc[m][n], 0, 0, 0);

    __syncthreads();   // all waves done reading before next stage overwrites
  }

  // Epilogue. C/D map (m89/m91): col = lane&15, row = (lane>>4)*4 + j.
  const int fq = (lane >> 4) * 4;
#pragma unroll
  for (int n = 0; n < 4; ++n) {
    const int col = bcol + wc * 64 + n * 16 + fr;
    const float bb = bias[col];
#pragma unroll
    for (int m = 0; m < 4; ++m) {
      const int row = brow + wr * 64 + m * 16 + fq;
      f32x4 v = acc[m][n];
#pragma unroll
      for (int j = 0; j < 4; ++j)
        out[(size_t)(row + j) * N_DIM + col] = v[j] + bb;
    }
  }
}

// ---------------------------------------------------------------------------
extern "C" void kernel_launch(void* const* d_in, const int* in_sizes, int n_in,
                              void* d_out, int out_size, void* d_ws, size_t ws_size,
                              hipStream_t stream) {
  const float* x    = (const float*)d_in[0];
  const float* W    = (const float*)d_in[1];
  const float* bias = (const float*)d_in[2];
  const float* lA   = (const float*)d_in[3];
  const float* lB   = (const float*)d_in[4];
  float* out = (float*)d_out;

  unsigned short* xb  = (unsigned short*)d_ws;                    // 8192*4096*2  = 64 MiB
  unsigned short* awb = xb + (size_t)M_DIM * K_DIM;               // 4096*4096*2  = 32 MiB

  aw_kernel<<<dim3(K_DIM / 512, N_DIM / 32), 256, 0, stream>>>(W, lA, lB, awb);
  cvt_kernel<<<2048, 256, 0, stream>>>(x, xb);
  gemm_kernel<<<(M_DIM / BM) * (N_DIM / BN), 256, 0, stream>>>(xb, awb, bias, out);
}

// Round 2
// 311.073 us; speedup vs baseline: 1.3411x; 1.3411x over previous
//
#include <hip/hip_runtime.h>
#include <hip/hip_bf16.h>
#include <stdint.h>

// Problem dims: B=4, S=2048 -> M=8192; IN=K=4096; OUT=N=4096; R=16
#define M_DIM 8192
#define N_DIM 4096
#define K_DIM 4096
#define R_DIM 16

typedef __bf16 bf16x8 __attribute__((ext_vector_type(8)));
typedef float f32x4 __attribute__((ext_vector_type(4)));
typedef unsigned short u16x8 __attribute__((ext_vector_type(8)));

#define AS1(p) ((const __attribute__((address_space(1))) void*)(p))
#define AS3(p) ((__attribute__((address_space(3))) void*)(p))

// Barrier with compiler-level memory fences on both sides (raw s_barrier is
// not a compiler memory barrier; the fences pin ds/vmem ops inside phases).
#define BAR() do { asm volatile("" ::: "memory"); __builtin_amdgcn_s_barrier(); asm volatile("" ::: "memory"); } while (0)
#define LGKM0() asm volatile("s_waitcnt lgkmcnt(0)" ::: "memory")
#define VMCNT4() asm volatile("s_waitcnt vmcnt(4)" ::: "memory")
#define VMCNT0() asm volatile("s_waitcnt vmcnt(0)" ::: "memory")

__device__ __forceinline__ unsigned short f2bf(float f) {
  unsigned u = __builtin_bit_cast(unsigned, f);
  u += 0x7FFFu + ((u >> 16) & 1u);   // round-to-nearest-even
  return (unsigned short)(u >> 16);
}

// ---------------------------------------------------------------------------
// Adapted weight: awb[o,i] = bf16( W[o,i] * (1 + sum_r A[r,i]*B[o,r]) )
// ---------------------------------------------------------------------------
__global__ void __launch_bounds__(256) aw_kernel(
    const float* __restrict__ W, const float* __restrict__ lA,
    const float* __restrict__ lB, unsigned short* __restrict__ awb) {
  __shared__ float Asub[16 * 512];
  __shared__ float Bsub[32 * 16];
  const int i0 = blockIdx.x * 512;
  const int o0 = blockIdx.y * 32;
  const int tid = threadIdx.x;

  for (int idx = tid; idx < 16 * 512; idx += 256) {
    int r = idx >> 9, i = idx & 511;
    Asub[idx] = lA[r * K_DIM + i0 + i];
  }
  for (int idx = tid; idx < 32 * 16; idx += 256) {
    int o = idx >> 4, r = idx & 15;
    Bsub[idx] = lB[(o0 + o) * R_DIM + r];
  }
  __syncthreads();

  for (int idx = tid; idx < 32 * 512; idx += 256) {
    int o = idx >> 9, i = idx & 511;
    float s = 1.0f;
#pragma unroll
    for (int r = 0; r < 16; ++r) s += Asub[r * 512 + i] * Bsub[o * 16 + r];
    size_t g = (size_t)(o0 + o) * K_DIM + i0 + i;
    awb[g] = f2bf(W[g] * s);
  }
}

// ---------------------------------------------------------------------------
// x (fp32) -> bf16 bits, vectorized.
// ---------------------------------------------------------------------------
__global__ void __launch_bounds__(256) cvt_kernel(const float* __restrict__ x,
                                                  unsigned short* __restrict__ xb) {
  const long total = (long)M_DIM * K_DIM;
  long i = ((long)blockIdx.x * 256 + threadIdx.x) * 8;
  const long stride = (long)gridDim.x * 256 * 8;
  for (; i < total; i += stride) {
    const float4* p = (const float4*)(x + i);
    float4 f0 = p[0], f1 = p[1];
    u16x8 v;
    v[0] = f2bf(f0.x); v[1] = f2bf(f0.y); v[2] = f2bf(f0.z); v[3] = f2bf(f0.w);
    v[4] = f2bf(f1.x); v[5] = f2bf(f1.y); v[6] = f2bf(f1.z); v[7] = f2bf(f1.w);
    *(u16x8*)(xb + i) = v;
  }
}

// ---------------------------------------------------------------------------
// GEMM: out[m,n] = sum_k xb[m,k]*awb[n,k] + bias[n]
// 256x256 tile, BK=64, 8 waves (2Mx4N), 8-phase pipeline with counted vmcnt
// (T3+T4), st_16x32 LDS swizzle (T2), setprio around MFMA (T5), XCD swizzle.
// LDS: 2 bufs x (A 256x64 | B 256x64) bf16 = 128 KiB. Each tile = 2 halves of
// 128x64 stored as 16x32-subtiled + XOR-swizzled; global_load_lds writes
// linearly, so the per-lane GLOBAL source is pre-permuted with the inverse map.
// ---------------------------------------------------------------------------
__global__ void __launch_bounds__(512, 2) gemm_kernel(
    const unsigned short* __restrict__ Ag,   // [M][K] bf16 bits (x)
    const unsigned short* __restrict__ Bg,   // [N][K] bf16 bits (adapted W)
    const float* __restrict__ bias,
    float* __restrict__ out) {
  __shared__ __attribute__((aligned(16))) unsigned short LDS[2 * 32768];

  // Bijective XCD swizzle: grid = 32*16 = 512, 512 % 8 == 0.
  const int nwg = gridDim.x;
  const int q8 = nwg >> 3;
  const int wg = blockIdx.x;
  const int swz = (wg & 7) * q8 + (wg >> 3);
  const int tiles_n = N_DIM / 256;           // 16
  const int brow = (swz / tiles_n) * 256;
  const int bcol = (swz % tiles_n) * 256;

  const int tid = threadIdx.x;
  const int lane = tid & 63;
  const int w = tid >> 6;                    // wave 0..7
  const int wr = w >> 2, wc = w & 3;         // 2 x 4 wave grid
  const int fr = lane & 15;
  const int kq = (lane >> 4) << 3;           // 0,8,16,24

  // ---- staging source map (inverse of st_16x32 swizzle; see derivation) ----
  // thread t, issue q covers LDS bytes [q*8192 + t*16, +16) of a half-tile;
  // maps to element (r, c): r = q*64 + (w>>1)*16 + rr, c = (w&1)*32 + cc.
  const int rr = lane >> 2;
  const int cc = ((lane & 1) << 3) | ((((lane >> 1) ^ (lane >> 5)) & 1) << 4);
  const int c_sw = ((w & 1) << 5) | cc;
  const int rbase = ((w >> 1) << 4) + rr;

  const unsigned short* srcA[2][2];          // [half][q]
#pragma unroll
  for (int h = 0; h < 2; ++h)
#pragma unroll
    for (int q = 0; q < 2; ++q)
      srcA[h][q] = Ag + (size_t)(brow + h * 128 + q * 64 + rbase) * K_DIM + c_sw;
  const long long bdelta = (long long)(Bg - Ag) + (long long)(bcol - brow) * K_DIM;

  // stage one half-tile (2 x global_load_lds, 16B/lane); dest is wave-uniform
  auto stageA = [&](int buf, int h, int kt) {
#pragma unroll
    for (int q = 0; q < 2; ++q)
      __builtin_amdgcn_global_load_lds(AS1(srcA[h][q] + (size_t)kt * 64),
          AS3(&LDS[buf * 32768 + h * 8192 + q * 4096 + w * 512]), 16, 0, 0);
  };
  auto stageB = [&](int buf, int h, int kt) {
#pragma unroll
    for (int q = 0; q < 2; ++q)
      __builtin_amdgcn_global_load_lds(AS1(srcA[h][q] + bdelta + (size_t)kt * 64),
          AS3(&LDS[buf * 32768 + 16384 + h * 8192 + q * 4096 + w * 512]), 16, 0, 0);
  };

  // ---- swizzled ds_read addressing ----
  // byte within subtile-row layout: (fr*64 + kq*2) ^ ((fr&8) ? 32 : 0)
  const int rdsw = ((fr << 6) | (kq << 1)) ^ ((fr & 8) << 2);
  auto lda = [&](int buf, int m, int kk) -> bf16x8 {
    return *(const bf16x8*)((const char*)LDS +
        (buf * 65536 + wr * 16384 + (m * 2 + kk) * 1024 + rdsw));
  };
  auto ldb = [&](int buf, int n, int kk) -> bf16x8 {
    return *(const bf16x8*)((const char*)LDS +
        (buf * 65536 + 32768 + (wc >> 1) * 16384 +
         (((wc & 1) * 4 + n) * 2 + kk) * 1024 + rdsw));
  };

  f32x4 acc[8][4] = {};
  bf16x8 a[2][4], b[2][4];

  auto load_a_group = [&](int buf, int mg) {
#pragma unroll
    for (int kk = 0; kk < 2; ++kk)
#pragma unroll
      for (int mi = 0; mi < 4; ++mi)
        a[kk][mi] = lda(buf, mg + mi, kk);
  };
  auto load_b_pair = [&](int buf, int nb) {
#pragma unroll
    for (int kk = 0; kk < 2; ++kk)
#pragma unroll
      for (int ni = 0; ni < 2; ++ni)
        b[kk][nb + ni] = ldb(buf, nb + ni, kk);
  };
  auto mma_quad = [&](int mb, int nb) {
#pragma unroll
    for (int mi = 0; mi < 4; ++mi)
#pragma unroll
      for (int ni = 0; ni < 2; ++ni)
#pragma unroll
        for (int kk = 0; kk < 2; ++kk)
          acc[mb + mi][nb + ni] = __builtin_amdgcn_mfma_f32_16x16x32_bf16(
              a[kk][mi], b[kk][nb + ni], acc[mb + mi][nb + ni], 0, 0, 0);
  };

  // ---- prologue: t0 -> buf0 (4 half-tiles), t1.B -> buf1 (2 half-tiles) ----
  stageB(0, 0, 0); stageB(0, 1, 0); stageA(0, 0, 0); stageA(0, 1, 0);
  stageB(1, 0, 1); stageB(1, 1, 1);
  VMCNT4();   // 12 issued, confirm oldest 8 = all of t0; t1.B stays in flight
  BAR();

  // ---- main loop: 2 K-tiles / iteration, 8 phases ----
#pragma unroll 1
  for (int i = 0; i < K_DIM / 128; ++i) {
    const bool more = (i < K_DIM / 128 - 1);
    const int t_odd = 2 * i + 1, t_nx0 = 2 * i + 2, t_nx1 = 2 * i + 3;

    // ===== K-tile 2i on buf0 =====
    // ph1: read A m0-3 + B n0-1 (12 ds_reads); stage buf1.A0 <- t_odd
    load_a_group(0, 0); load_b_pair(0, 0);
    stageA(1, 0, t_odd);
    BAR(); LGKM0();
    __builtin_amdgcn_s_setprio(1); mma_quad(0, 0); __builtin_amdgcn_s_setprio(0);
    BAR();
    // ph2: read B n2-3; stage buf1.A1 <- t_odd
    load_b_pair(0, 2);
    stageA(1, 1, t_odd);
    BAR(); LGKM0();
    __builtin_amdgcn_s_setprio(1); mma_quad(0, 2); __builtin_amdgcn_s_setprio(0);
    BAR();
    // ph3: read A m4-7; stage buf0.B0 <- t_nx0 (B of buf0 fully read by ph2)
    load_a_group(0, 4);
    if (more) stageB(0, 0, t_nx0);
    BAR(); LGKM0();
    __builtin_amdgcn_s_setprio(1); mma_quad(4, 2); __builtin_amdgcn_s_setprio(0);
    BAR();
    // ph4: no reads; stage buf0.B1 <- t_nx0; counted vmcnt confirms all t_odd
    if (more) stageB(0, 1, t_nx0);
    BAR();
    __builtin_amdgcn_s_setprio(1); mma_quad(4, 0); __builtin_amdgcn_s_setprio(0);
    if (more) { VMCNT4(); } else { VMCNT0(); }
    BAR();

    // ===== K-tile 2i+1 on buf1 =====
    // ph5: read A m0-3 + B n0-1; stage buf0.A0 <- t_nx0 (A of buf0 read by ph3)
    load_a_group(1, 0); load_b_pair(1, 0);
    if (more) stageA(0, 0, t_nx0);
    BAR(); LGKM0();
    __builtin_amdgcn_s_setprio(1); mma_quad(0, 0); __builtin_amdgcn_s_setprio(0);
    BAR();
    // ph6: read B n2-3; stage buf0.A1 <- t_nx0
    load_b_pair(1, 2);
    if (more) stageA(0, 1, t_nx0);
    BAR(); LGKM0();
    __builtin_amdgcn_s_setprio(1); mma_quad(0, 2); __builtin_amdgcn_s_setprio(0);
    BAR();
    // ph7: read A m4-7; stage buf1.B0 <- t_nx1
    load_a_group(1, 4);
    if (more) stageB(1, 0, t_nx1);
    BAR(); LGKM0();
    __builtin_amdgcn_s_setprio(1); mma_quad(4, 2); __builtin_amdgcn_s_setprio(0);
    BAR();
    // ph8: stage buf1.B1 <- t_nx1; counted vmcnt confirms all t_nx0
    if (more) stageB(1, 1, t_nx1);
    BAR();
    __builtin_amdgcn_s_setprio(1); mma_quad(4, 0); __builtin_amdgcn_s_setprio(0);
    if (more) { VMCNT4(); } else { VMCNT0(); }
    BAR();
  }

  // ---- epilogue: C/D map col = lane&15, row = (lane>>4)*4 + j ----
  const int fq = (lane >> 4) * 4;
#pragma unroll
  for (int n = 0; n < 4; ++n) {
    const int col = bcol + wc * 64 + n * 16 + fr;
    const float bb = bias[col];
#pragma unroll
    for (int m = 0; m < 8; ++m) {
      const int row = brow + wr * 128 + m * 16 + fq;
      f32x4 v = acc[m][n];
#pragma unroll
      for (int j = 0; j < 4; ++j)
        out[(size_t)(row + j) * N_DIM + col] = v[j] + bb;
    }
  }
}

// ---------------------------------------------------------------------------
extern "C" void kernel_launch(void* const* d_in, const int* in_sizes, int n_in,
                              void* d_out, int out_size, void* d_ws, size_t ws_size,
                              hipStream_t stream) {
  const float* x    = (const float*)d_in[0];
  const float* W    = (const float*)d_in[1];
  const float* bias = (const float*)d_in[2];
  const float* lA   = (const float*)d_in[3];
  const float* lB   = (const float*)d_in[4];
  float* out = (float*)d_out;

  unsigned short* xb  = (unsigned short*)d_ws;            // 64 MiB
  unsigned short* awb = xb + (size_t)M_DIM * K_DIM;       // 32 MiB

  aw_kernel<<<dim3(K_DIM / 512, N_DIM / 32), 256, 0, stream>>>(W, lA, lB, awb);
  cvt_kernel<<<2048, 256, 0, stream>>>(x, xb);
  gemm_kernel<<<(M_DIM / 256) * (N_DIM / 256), 512, 0, stream>>>(xb, awb, bias, out);
}

// Round 3
// 302.557 us; speedup vs baseline: 1.3789x; 1.0281x over previous
//
#include <hip/hip_runtime.h>
#include <hip/hip_bf16.h>
#include <stdint.h>

// Problem dims: B=4, S=2048 -> M=8192; IN=K=4096; OUT=N=4096; R=16
#define M_DIM 8192
#define N_DIM 4096
#define K_DIM 4096
#define R_DIM 16

typedef __bf16 bf16x8 __attribute__((ext_vector_type(8)));
typedef float f32x4 __attribute__((ext_vector_type(4)));
typedef unsigned short u16x8 __attribute__((ext_vector_type(8)));

#define AS1(p) ((const __attribute__((address_space(1))) void*)(p))
#define AS3(p) ((__attribute__((address_space(3))) void*)(p))

#define BAR() do { asm volatile("" ::: "memory"); __builtin_amdgcn_s_barrier(); asm volatile("" ::: "memory"); } while (0)
#define LGKM0() asm volatile("s_waitcnt lgkmcnt(0)" ::: "memory")
#define VMCNT6() asm volatile("s_waitcnt vmcnt(6)" ::: "memory")
#define VMCNT0() asm volatile("s_waitcnt vmcnt(0)" ::: "memory")

__device__ __forceinline__ unsigned short f2bf(float f) {
  unsigned u = __builtin_bit_cast(unsigned, f);
  u += 0x7FFFu + ((u >> 16) & 1u);   // round-to-nearest-even
  return (unsigned short)(u >> 16);
}

// ---------------------------------------------------------------------------
// prep: blocks [0,1024): awb[o,i] = bf16(W[o,i]*(1+sum_r A[r,i]*B[o,r]))
//       blocks [1024,5120): xb = bf16(x), vectorized grid-stride
// ---------------------------------------------------------------------------
#define CVT_BLOCKS 4096
__global__ void __launch_bounds__(256) prep_kernel(
    const float* __restrict__ x, const float* __restrict__ W,
    const float* __restrict__ lA, const float* __restrict__ lB,
    unsigned short* __restrict__ xb, unsigned short* __restrict__ awb) {
  __shared__ float Asub[16 * 512];
  __shared__ float Bsub[32 * 16];
  const int tid = threadIdx.x;

  if (blockIdx.x < 1024) {
    const int i0 = (blockIdx.x & 7) * 512;
    const int o0 = (blockIdx.x >> 3) * 32;
    for (int idx = tid; idx < 16 * 512; idx += 256) {
      int r = idx >> 9, i = idx & 511;
      Asub[idx] = lA[r * K_DIM + i0 + i];
    }
    for (int idx = tid; idx < 32 * 16; idx += 256) {
      int o = idx >> 4, r = idx & 15;
      Bsub[idx] = lB[(o0 + o) * R_DIM + r];
    }
    __syncthreads();
    for (int idx = tid; idx < 32 * 512; idx += 256) {
      int o = idx >> 9, i = idx & 511;
      float s = 1.0f;
#pragma unroll
      for (int r = 0; r < 16; ++r) s += Asub[r * 512 + i] * Bsub[o * 16 + r];
      size_t g = (size_t)(o0 + o) * K_DIM + i0 + i;
      awb[g] = f2bf(W[g] * s);
    }
  } else {
    const long total = (long)M_DIM * K_DIM;
    long i = ((long)(blockIdx.x - 1024) * 256 + tid) * 8;
    const long stride = (long)CVT_BLOCKS * 256 * 8;
    for (; i < total; i += stride) {
      const float4* p = (const float4*)(x + i);
      float4 f0 = p[0], f1 = p[1];
      u16x8 v;
      v[0] = f2bf(f0.x); v[1] = f2bf(f0.y); v[2] = f2bf(f0.z); v[3] = f2bf(f0.w);
      v[4] = f2bf(f1.x); v[5] = f2bf(f1.y); v[6] = f2bf(f1.z); v[7] = f2bf(f1.w);
      *(u16x8*)(xb + i) = v;
    }
  }
}

// ---------------------------------------------------------------------------
// GEMM: out[m,n] = sum_k xb[m,k]*awb[n,k] + bias[n]
// 256x256 tile, BK=64, 8 waves (2Mx4N), 8-phase pipeline. Stages are spread
// 1 half-tile/phase (2 in ph3/ph7), waits are vmcnt(6) at ph4/ph8 so the
// newest awaited load always has >=3 phases of cover (m201/T4 formula:
// N = 2 loads/half-tile x 3 half-tiles in flight). st_16x32 swizzle (T2),
// setprio around MFMA (T5), bijective XCD swizzle (T1).
// ---------------------------------------------------------------------------
__global__ void __launch_bounds__(512, 2) gemm_kernel(
    const unsigned short* __restrict__ Ag,   // [M][K] bf16 bits (x)
    const unsigned short* __restrict__ Bg,   // [N][K] bf16 bits (adapted W)
    const float* __restrict__ bias,
    float* __restrict__ out) {
  __shared__ __attribute__((aligned(16))) unsigned short LDS[2 * 32768];

  // Bijective XCD swizzle: grid = 32*16 = 512, 512 % 8 == 0.
  const int nwg = gridDim.x;
  const int q8 = nwg >> 3;
  const int wg = blockIdx.x;
  const int swz = (wg & 7) * q8 + (wg >> 3);
  const int tiles_n = N_DIM / 256;           // 16
  const int brow = (swz / tiles_n) * 256;
  const int bcol = (swz % tiles_n) * 256;

  const int tid = threadIdx.x;
  const int lane = tid & 63;
  const int w = tid >> 6;                    // wave 0..7
  const int wr = w >> 2, wc = w & 3;         // 2 x 4 wave grid
  const int fr = lane & 15;
  const int kq = (lane >> 4) << 3;           // 0,8,16,24

  // staging source map (inverse of st_16x32 swizzle)
  const int rr = lane >> 2;
  const int cc = ((lane & 1) << 3) | ((((lane >> 1) ^ (lane >> 5)) & 1) << 4);
  const int c_sw = ((w & 1) << 5) | cc;
  const int rbase = ((w >> 1) << 4) + rr;

  const unsigned short* srcA[2][2];          // [half][q]
#pragma unroll
  for (int h = 0; h < 2; ++h)
#pragma unroll
    for (int q = 0; q < 2; ++q)
      srcA[h][q] = Ag + (size_t)(brow + h * 128 + q * 64 + rbase) * K_DIM + c_sw;
  const long long bdelta = (long long)(Bg - Ag) + (long long)(bcol - brow) * K_DIM;

  auto stageA = [&](int buf, int h, int kt) {
#pragma unroll
    for (int q = 0; q < 2; ++q)
      __builtin_amdgcn_global_load_lds(AS1(srcA[h][q] + (size_t)kt * 64),
          AS3(&LDS[buf * 32768 + h * 8192 + q * 4096 + w * 512]), 16, 0, 0);
  };
  auto stageB = [&](int buf, int h, int kt) {
#pragma unroll
    for (int q = 0; q < 2; ++q)
      __builtin_amdgcn_global_load_lds(AS1(srcA[h][q] + bdelta + (size_t)kt * 64),
          AS3(&LDS[buf * 32768 + 16384 + h * 8192 + q * 4096 + w * 512]), 16, 0, 0);
  };

  // swizzled ds_read addressing
  const int rdsw = ((fr << 6) | (kq << 1)) ^ ((fr & 8) << 2);
  auto lda = [&](int buf, int m, int kk) -> bf16x8 {
    return *(const bf16x8*)((const char*)LDS +
        (buf * 65536 + wr * 16384 + (m * 2 + kk) * 1024 + rdsw));
  };
  auto ldb = [&](int buf, int n, int kk) -> bf16x8 {
    return *(const bf16x8*)((const char*)LDS +
        (buf * 65536 + 32768 + (wc >> 1) * 16384 +
         (((wc & 1) * 4 + n) * 2 + kk) * 1024 + rdsw));
  };

  f32x4 acc[8][4] = {};
  bf16x8 a[2][4], b[2][4];

  auto load_a_group = [&](int buf, int mg) {
#pragma unroll
    for (int kk = 0; kk < 2; ++kk)
#pragma unroll
      for (int mi = 0; mi < 4; ++mi)
        a[kk][mi] = lda(buf, mg + mi, kk);
  };
  auto load_b_pair = [&](int buf, int nb) {
#pragma unroll
    for (int kk = 0; kk < 2; ++kk)
#pragma unroll
      for (int ni = 0; ni < 2; ++ni)
        b[kk][nb + ni] = ldb(buf, nb + ni, kk);
  };
  auto mma_quad = [&](int mb, int nb) {
#pragma unroll
    for (int mi = 0; mi < 4; ++mi)
#pragma unroll
      for (int ni = 0; ni < 2; ++ni)
#pragma unroll
        for (int kk = 0; kk < 2; ++kk)
          acc[mb + mi][nb + ni] = __builtin_amdgcn_mfma_f32_16x16x32_bf16(
              a[kk][mi], b[kk][nb + ni], acc[mb + mi][nb + ni], 0, 0, 0);
  };

  // prologue: t0 full (8 loads) + t1.B0,B1,A0 (6 loads); wait t0, keep 6 in flight
  stageB(0, 0, 0); stageB(0, 1, 0); stageA(0, 0, 0); stageA(0, 1, 0);
  stageB(1, 0, 1); stageB(1, 1, 1); stageA(1, 0, 1);
  VMCNT6();
  BAR();

  // main loop: 2 K-tiles / iteration, 8 phases, 1 half-tile staged per phase
#pragma unroll 1
  for (int i = 0; i < K_DIM / 128; ++i) {
    const bool more = (i < K_DIM / 128 - 1);
    const int t_cur1 = 2 * i + 1, t_nx0 = 2 * i + 2, t_nx1 = 2 * i + 3;

    // ===== K-tile 2i on buf0 =====
    // ph1: read A m0-3 + B n0-1; stage buf1.A1 <- t_cur1 (prev buf1.A read done prev ph7)
    load_a_group(0, 0); load_b_pair(0, 0);
    stageA(1, 1, t_cur1);
    BAR(); LGKM0();
    __builtin_amdgcn_s_setprio(1); mma_quad(0, 0); __builtin_amdgcn_s_setprio(0);
    BAR();
    // ph2: read B n2-3
    load_b_pair(0, 2);
    BAR(); LGKM0();
    __builtin_amdgcn_s_setprio(1); mma_quad(0, 2); __builtin_amdgcn_s_setprio(0);
    BAR();
    // ph3: read A m4-7; stage buf0.B0+B1 <- t_nx0 (buf0.B read done ph2)
    load_a_group(0, 4);
    if (more) { stageB(0, 0, t_nx0); stageB(0, 1, t_nx0); }
    BAR(); LGKM0();
    __builtin_amdgcn_s_setprio(1); mma_quad(4, 2); __builtin_amdgcn_s_setprio(0);
    BAR();
    // ph4: stage buf0.A0 <- t_nx0 (buf0.A read done ph3); wait: t_cur1 landed
    if (more) stageA(0, 0, t_nx0);
    BAR();
    __builtin_amdgcn_s_setprio(1); mma_quad(4, 0); __builtin_amdgcn_s_setprio(0);
    if (more) { VMCNT6(); } else { VMCNT0(); }
    BAR();

    // ===== K-tile 2i+1 on buf1 =====
    // ph5: read A m0-3 + B n0-1; stage buf0.A1 <- t_nx0
    load_a_group(1, 0); load_b_pair(1, 0);
    if (more) stageA(0, 1, t_nx0);
    BAR(); LGKM0();
    __builtin_amdgcn_s_setprio(1); mma_quad(0, 0); __builtin_amdgcn_s_setprio(0);
    BAR();
    // ph6: read B n2-3
    load_b_pair(1, 2);
    BAR(); LGKM0();
    __builtin_amdgcn_s_setprio(1); mma_quad(0, 2); __builtin_amdgcn_s_setprio(0);
    BAR();
    // ph7: read A m4-7; stage buf1.B0+B1 <- t_nx1 (buf1.B read done ph6)
    load_a_group(1, 4);
    if (more) { stageB(1, 0, t_nx1); stageB(1, 1, t_nx1); }
    BAR(); LGKM0();
    __builtin_amdgcn_s_setprio(1); mma_quad(4, 2); __builtin_amdgcn_s_setprio(0);
    BAR();
    // ph8: stage buf1.A0 <- t_nx1 (buf1.A read done ph7); wait: t_nx0 landed
    if (more) stageA(1, 0, t_nx1);
    BAR();
    __builtin_amdgcn_s_setprio(1); mma_quad(4, 0); __builtin_amdgcn_s_setprio(0);
    if (more) VMCNT6();
    BAR();
  }

  // epilogue: C/D map col = lane&15, row = (lane>>4)*4 + j
  const int fq = (lane >> 4) * 4;
#pragma unroll
  for (int n = 0; n < 4; ++n) {
    const int col = bcol + wc * 64 + n * 16 + fr;
    const float bb = bias[col];
#pragma unroll
    for (int m = 0; m < 8; ++m) {
      const int row = brow + wr * 128 + m * 16 + fq;
      f32x4 v = acc[m][n];
#pragma unroll
      for (int j = 0; j < 4; ++j)
        out[(size_t)(row + j) * N_DIM + col] = v[j] + bb;
    }
  }
}

// ---------------------------------------------------------------------------
extern "C" void kernel_launch(void* const* d_in, const int* in_sizes, int n_in,
                              void* d_out, int out_size, void* d_ws, size_t ws_size,
                              hipStream_t stream) {
  const float* x    = (const float*)d_in[0];
  const float* W    = (const float*)d_in[1];
  const float* bias = (const float*)d_in[2];
  const float* lA   = (const float*)d_in[3];
  const float* lB   = (const float*)d_in[4];
  float* out = (float*)d_out;

  unsigned short* xb  = (unsigned short*)d_ws;            // 64 MiB
  unsigned short* awb = xb + (size_t)M_DIM * K_DIM;       // 32 MiB

  prep_kernel<<<1024 + CVT_BLOCKS, 256, 0, stream>>>(x, W, lA, lB, xb, awb);
  gemm_kernel<<<(M_DIM / 256) * (N_DIM / 256), 512, 0, stream>>>(xb, awb, bias, out);
}

// Round 4
// 294.149 us; speedup vs baseline: 1.4183x; 1.0286x over previous
//
#include <hip/hip_runtime.h>
#include <hip/hip_bf16.h>
#include <stdint.h>

// Problem dims: B=4, S=2048 -> M=8192; IN=K=4096; OUT=N=4096; R=16
#define M_DIM 8192
#define N_DIM 4096
#define K_DIM 4096
#define R_DIM 16

typedef __bf16 bf16x8 __attribute__((ext_vector_type(8)));
typedef float f32x4 __attribute__((ext_vector_type(4)));
typedef unsigned short u16x8 __attribute__((ext_vector_type(8)));

#define AS1(p) ((const __attribute__((address_space(1))) void*)(p))
#define AS3(p) ((__attribute__((address_space(3))) void*)(p))

#define BAR() do { asm volatile("" ::: "memory"); __builtin_amdgcn_s_barrier(); asm volatile("" ::: "memory"); } while (0)
#define VMCNT2() asm volatile("s_waitcnt vmcnt(2)" ::: "memory")
#define VMCNT0() asm volatile("s_waitcnt vmcnt(0)" ::: "memory")
#define VMCNT8() asm volatile("s_waitcnt vmcnt(8)" ::: "memory")

__device__ __forceinline__ unsigned short f2bf(float f) {
  unsigned u = __builtin_bit_cast(unsigned, f);
  u += 0x7FFFu + ((u >> 16) & 1u);   // round-to-nearest-even
  return (unsigned short)(u >> 16);
}

// ---------------------------------------------------------------------------
// prep: blocks [0,1024): awb[o,i] = bf16(W[o,i]*(1+sum_r A[r,i]*B[o,r]))
//       blocks [1024,5120): xb = bf16(x), vectorized grid-stride
// ---------------------------------------------------------------------------
#define CVT_BLOCKS 4096
__global__ void __launch_bounds__(256) prep_kernel(
    const float* __restrict__ x, const float* __restrict__ W,
    const float* __restrict__ lA, const float* __restrict__ lB,
    unsigned short* __restrict__ xb, unsigned short* __restrict__ awb) {
  __shared__ float Asub[16 * 512];
  __shared__ float Bsub[32 * 16];
  const int tid = threadIdx.x;

  if (blockIdx.x < 1024) {
    const int i0 = (blockIdx.x & 7) * 512;
    const int o0 = (blockIdx.x >> 3) * 32;
    for (int idx = tid; idx < 16 * 512; idx += 256) {
      int r = idx >> 9, i = idx & 511;
      Asub[idx] = lA[r * K_DIM + i0 + i];
    }
    for (int idx = tid; idx < 32 * 16; idx += 256) {
      int o = idx >> 4, r = idx & 15;
      Bsub[idx] = lB[(o0 + o) * R_DIM + r];
    }
    __syncthreads();
    for (int idx = tid; idx < 32 * 512; idx += 256) {
      int o = idx >> 9, i = idx & 511;
      float s = 1.0f;
#pragma unroll
      for (int r = 0; r < 16; ++r) s += Asub[r * 512 + i] * Bsub[o * 16 + r];
      size_t g = (size_t)(o0 + o) * K_DIM + i0 + i;
      awb[g] = f2bf(W[g] * s);
    }
  } else {
    const long total = (long)M_DIM * K_DIM;
    long i = ((long)(blockIdx.x - 1024) * 256 + tid) * 8;
    const long stride = (long)CVT_BLOCKS * 256 * 8;
    for (; i < total; i += stride) {
      const float4* p = (const float4*)(x + i);
      float4 f0 = p[0], f1 = p[1];
      u16x8 v;
      v[0] = f2bf(f0.x); v[1] = f2bf(f0.y); v[2] = f2bf(f0.z); v[3] = f2bf(f0.w);
      v[4] = f2bf(f1.x); v[5] = f2bf(f1.y); v[6] = f2bf(f1.z); v[7] = f2bf(f1.w);
      *(u16x8*)(xb + i) = v;
    }
  }
}

// ---------------------------------------------------------------------------
// GEMM: out[m,n] = sum_k xb[m,k]*awb[n,k] + bias[n]
// 256x256 tile, BK=64, 8 waves (2Mx4N). Read-ahead 4-phase pipeline:
// fragments are ds_read one phase+ BEFORE their MFMA use (WAR-pinned in-place
// register reuse keeps frag regs at 64 VGPR), one raw s_barrier per phase, no
// block-wide lgkm drain (compiler emits fine-grained per-use lgkmcnt).
// vmcnt(2) publishes tile t+1 at end-P1 of tile t. st_16x32 swizzle (T2),
// setprio (T5), bijective XCD swizzle (T1).
// Ledger (tile t, buf=t&1; quadrants Q0:a_lo*b_lo Q1:a_lo*b_hi Q2:a_hi*b_hi
// Q3:a_hi*b_lo):
//   P0: mma Q0
//   P1: stage buf.B0<-t+2 | mma Q1 | read a_hi(t) | vmcnt(2) | BAR
//   P2: stage buf.B1,A0<-t+2 | mma Q2 | read b_hi(t+1) | BAR
//   P3: stage buf.A1<-t+2 | mma Q3 | read a_lo(t+1), b_lo(t+1) | BAR
// Stage-vs-read: every stage issues >=1 barrier after the last read of its
// region (writes land >=200cy after issue; reads execute <150cy after issue).
// vmcnt: end-P1(t) outstanding = 8 (t+1, staged P1-P3 of t-1) + 2 (B0 t+2).
// ---------------------------------------------------------------------------
__global__ void __launch_bounds__(512, 2) gemm_kernel(
    const unsigned short* __restrict__ Ag,   // [M][K] bf16 bits (x)
    const unsigned short* __restrict__ Bg,   // [N][K] bf16 bits (adapted W)
    const float* __restrict__ bias,
    float* __restrict__ out) {
  __shared__ __attribute__((aligned(16))) unsigned short LDS[2 * 32768];

  // Bijective XCD swizzle: grid = 32*16 = 512, 512 % 8 == 0.
  const int nwg = gridDim.x;
  const int q8 = nwg >> 3;
  const int wg = blockIdx.x;
  const int swz = (wg & 7) * q8 + (wg >> 3);
  const int tiles_n = N_DIM / 256;           // 16
  const int brow = (swz / tiles_n) * 256;
  const int bcol = (swz % tiles_n) * 256;

  const int tid = threadIdx.x;
  const int lane = tid & 63;
  const int w = tid >> 6;                    // wave 0..7
  const int wr = w >> 2, wc = w & 3;         // 2 x 4 wave grid
  const int fr = lane & 15;
  const int kq = (lane >> 4) << 3;           // 0,8,16,24

  // staging source map (inverse of st_16x32 swizzle)
  const int rr = lane >> 2;
  const int cc = ((lane & 1) << 3) | ((((lane >> 1) ^ (lane >> 5)) & 1) << 4);
  const int c_sw = ((w & 1) << 5) | cc;
  const int rbase = ((w >> 1) << 4) + rr;

  const unsigned short* srcA[2][2];          // [half][q]
#pragma unroll
  for (int h = 0; h < 2; ++h)
#pragma unroll
    for (int q = 0; q < 2; ++q)
      srcA[h][q] = Ag + (size_t)(brow + h * 128 + q * 64 + rbase) * K_DIM + c_sw;
  const long long bdelta = (long long)(Bg - Ag) + (long long)(bcol - brow) * K_DIM;

  auto stageA = [&](int buf, int h, int kt) {
#pragma unroll
    for (int q = 0; q < 2; ++q)
      __builtin_amdgcn_global_load_lds(AS1(srcA[h][q] + (size_t)kt * 64),
          AS3(&LDS[buf * 32768 + h * 8192 + q * 4096 + w * 512]), 16, 0, 0);
  };
  auto stageB = [&](int buf, int h, int kt) {
#pragma unroll
    for (int q = 0; q < 2; ++q)
      __builtin_amdgcn_global_load_lds(AS1(srcA[h][q] + bdelta + (size_t)kt * 64),
          AS3(&LDS[buf * 32768 + 16384 + h * 8192 + q * 4096 + w * 512]), 16, 0, 0);
  };

  // swizzled ds_read addressing
  const int rdsw = ((fr << 6) | (kq << 1)) ^ ((fr & 8) << 2);
  auto lda = [&](int buf, int m, int kk) -> bf16x8 {
    return *(const bf16x8*)((const char*)LDS +
        (buf * 65536 + wr * 16384 + (m * 2 + kk) * 1024 + rdsw));
  };
  auto ldb = [&](int buf, int n, int kk) -> bf16x8 {
    return *(const bf16x8*)((const char*)LDS +
        (buf * 65536 + 32768 + (wc >> 1) * 16384 +
         (((wc & 1) * 4 + n) * 2 + kk) * 1024 + rdsw));
  };

  f32x4 acc[8][4] = {};
  bf16x8 a[2][4];          // current A half (a_lo -> a_hi in-place per tile)
  bf16x8 blo[2][2], bhi[2][2];

  auto read_a = [&](int buf, int mg) {       // mg=0: a_lo, mg=4: a_hi
#pragma unroll
    for (int kk = 0; kk < 2; ++kk)
#pragma unroll
      for (int mi = 0; mi < 4; ++mi)
        a[kk][mi] = lda(buf, mg + mi, kk);
  };
  auto read_blo = [&](int buf) {
#pragma unroll
    for (int kk = 0; kk < 2; ++kk)
#pragma unroll
      for (int ni = 0; ni < 2; ++ni)
        blo[kk][ni] = ldb(buf, ni, kk);
  };
  auto read_bhi = [&](int buf) {
#pragma unroll
    for (int kk = 0; kk < 2; ++kk)
#pragma unroll
      for (int ni = 0; ni < 2; ++ni)
        bhi[kk][ni] = ldb(buf, 2 + ni, kk);
  };
  auto mma_b = [&](bf16x8 (&bb)[2][2], int am, int an) {
#pragma unroll
    for (int mi = 0; mi < 4; ++mi)
#pragma unroll
      for (int ni = 0; ni < 2; ++ni)
#pragma unroll
        for (int kk = 0; kk < 2; ++kk)
          acc[am + mi][an + ni] = __builtin_amdgcn_mfma_f32_16x16x32_bf16(
              a[kk][mi], bb[kk][ni], acc[am + mi][an + ni], 0, 0, 0);
  };

  // one tile = 4 phases; g2: stage t+2 exists; gr: tile t+1 exists
  auto tile_body = [&](int t, int buf, bool g2, bool gr) {
    const int nxbuf = buf ^ 1;
    // P0
    __builtin_amdgcn_s_setprio(1); mma_b(blo, 0, 0); __builtin_amdgcn_s_setprio(0);
    BAR();
    // P1
    if (g2) stageB(buf, 0, t + 2);
    __builtin_amdgcn_s_setprio(1); mma_b(bhi, 0, 2); __builtin_amdgcn_s_setprio(0);
    read_a(buf, 4);                          // a_hi(t), WAR-pinned after Q1
    if (g2) { VMCNT2(); } else { VMCNT0(); }
    BAR();
    // P2
    if (g2) { stageB(buf, 1, t + 2); stageA(buf, 0, t + 2); }
    __builtin_amdgcn_s_setprio(1); mma_b(bhi, 4, 2); __builtin_amdgcn_s_setprio(0);
    if (gr) read_bhi(nxbuf);                 // b_hi(t+1), WAR-pinned after Q2
    BAR();
    // P3
    if (g2) stageA(buf, 1, t + 2);
    __builtin_amdgcn_s_setprio(1); mma_b(blo, 4, 0); __builtin_amdgcn_s_setprio(0);
    if (gr) { read_a(nxbuf, 0); read_blo(nxbuf); }  // a_lo,b_lo(t+1)
    BAR();
  };

  // prologue: stage tiles 0 (buf0) and 1 (buf1); wait tile0; pre-read frags
  stageB(0, 0, 0); stageB(0, 1, 0); stageA(0, 0, 0); stageA(0, 1, 0);
  stageB(1, 0, 1); stageB(1, 1, 1); stageA(1, 0, 1); stageA(1, 1, 1);
  VMCNT8();
  BAR();
  read_bhi(0); read_a(0, 0); read_blo(0);    // tile0: b_hi, a_lo, b_lo

  // main loop: 32 pairs of tiles (NT = 64)
#pragma unroll 1
  for (int i = 0; i < 32; ++i) {
    const bool more = (i < 31);
    tile_body(2 * i,     0, more, true);
    tile_body(2 * i + 1, 1, more, more);
  }

  // epilogue: C/D map col = lane&15, row = (lane>>4)*4 + j
  const int fq = (lane >> 4) * 4;
#pragma unroll
  for (int n = 0; n < 4; ++n) {
    const int col = bcol + wc * 64 + n * 16 + fr;
    const float bb = bias[col];
#pragma unroll
    for (int m = 0; m < 8; ++m) {
      const int row = brow + wr * 128 + m * 16 + fq;
      f32x4 v = acc[m][n];
#pragma unroll
      for (int j = 0; j < 4; ++j)
        out[(size_t)(row + j) * N_DIM + col] = v[j] + bb;
    }
  }
}

// ---------------------------------------------------------------------------
extern "C" void kernel_launch(void* const* d_in, const int* in_sizes, int n_in,
                              void* d_out, int out_size, void* d_ws, size_t ws_size,
                              hipStream_t stream) {
  const float* x    = (const float*)d_in[0];
  const float* W    = (const float*)d_in[1];
  const float* bias = (const float*)d_in[2];
  const float* lA   = (const float*)d_in[3];
  const float* lB   = (const float*)d_in[4];
  float* out = (float*)d_out;

  unsigned short* xb  = (unsigned short*)d_ws;            // 64 MiB
  unsigned short* awb = xb + (size_t)M_DIM * K_DIM;       // 32 MiB

  prep_kernel<<<1024 + CVT_BLOCKS, 256, 0, stream>>>(x, W, lA, lB, xb, awb);
  gemm_kernel<<<(M_DIM / 256) * (N_DIM / 256), 512, 0, stream>>>(xb, awb, bias, out);
}